// Round 5
// baseline (332.146 us; speedup 1.0000x reference)
//
#include <hip/hip_runtime.h>
#include <hip/hip_bf16.h>
#include <cstdint>

// DifferentiableILP on MI355X (gfx950).
// A = softmax(rule_weights[:,0,:]); 3x: facts = max(facts, colmax(A @ facts)).
// Columns independent -> each block owns a column stripe; ft immutable in LDS,
// running col-max folded into the B fragment at load time (packed u16 max).
//
// R7 changes vs R6 (ilp 153us, MfmaUtil 28.6%, Occ 40%, conflicts 0):
//  - ROOT CAUSE: A-fragment re-reads. Each block reads all of A (512KB) per
//    iteration; at NT=64 that is 1.6GB from L2 -> demands ~36 TB/s to match
//    the 44us MFMA floor, >100% of the 34.5 TB/s L2 ceiling. GEMM span was
//    L2-BW-bound (~2x over), which is why occupancy/prefetch fixes were null.
//  - NT=64 -> 128: halves block count and A-traffic (0.8GB -> ~50% L2 load).
//    ft = 128KB LDS -> 1 block/CU; 1024-thread blocks (16 waves = 4/SIMD,
//    same occupancy). Per wave: 32 rows x 128 cols -> acc[4] = 64 AGPR.
//  - Register diet for the 128-reg tier a 16-wave block requires:
//    bR single-buffered distance-1 (LDS latency ~120cy << ~512cy MFMA round),
//    aF stays double-buffered distance-2 (covers L2 latency).

typedef __attribute__((ext_vector_type(8))) short bf16x8;   // 8 bf16 = 4 VGPRs
typedef __attribute__((ext_vector_type(8))) unsigned short u16x8;
typedef __attribute__((ext_vector_type(16))) float f32x16;  // 32x32 accumulator
typedef unsigned short ushort_t;
typedef unsigned int uint32;

#define PDIM 512
#define CDIM 65536
#define NT   128     // columns per block
#define WAVES 16

__device__ __forceinline__ ushort_t f2bf(float x) {          // RNE float->bf16
    uint32 u = __float_as_uint(x);
    return (ushort_t)((u + 0x7fffu + ((u >> 16) & 1u)) >> 16);
}
__device__ __forceinline__ float bf2f(uint32 bits) { return __uint_as_float(bits << 16); }

// packed max(v, splat(mu)) in the u16 domain (valid: all values are nonneg bf16)
__device__ __forceinline__ bf16x8 pkmax8(bf16x8 v, ushort_t mu) {
    u16x8 a = __builtin_bit_cast(u16x8, v);
    const u16x8 mb = {mu, mu, mu, mu, mu, mu, mu, mu};
    a = __builtin_elementwise_max(a, mb);
    return __builtin_bit_cast(bf16x8, a);
}

// ---- phase 1: softmax row r, packed fragment-linear for 32x32x16 MFMA.
// chunk idx16 = (kt2*16 + (r>>5))*64 + half*32 + (r&31) holds
// A[r][kt2*16 + half*8 .. +7] as 8 bf16.  (unchanged from R5/R6)
__global__ __launch_bounds__(64) void softmax_pack(const float* __restrict__ rw,
                                                   ushort_t* __restrict__ Apk) {
    const int r  = blockIdx.x;
    const int ln = threadIdx.x;
    const float* row = rw + r * PDIM;
    float4 x0 = *(const float4*)(row + ln * 8);
    float4 x1 = *(const float4*)(row + ln * 8 + 4);
    float v[8] = {x0.x, x0.y, x0.z, x0.w, x1.x, x1.y, x1.z, x1.w};

    float mx = -1e30f;
    #pragma unroll
    for (int i = 0; i < 8; ++i) mx = fmaxf(mx, v[i]);
    #pragma unroll
    for (int d = 1; d < 64; d <<= 1) mx = fmaxf(mx, __shfl_xor(mx, d, 64));
    float s = 0.f;
    #pragma unroll
    for (int i = 0; i < 8; ++i) { v[i] = __expf(v[i] - mx); s += v[i]; }
    #pragma unroll
    for (int d = 1; d < 64; d <<= 1) s += __shfl_xor(s, d, 64);
    const float inv = 1.f / s;

    ushort_t o[8];
    #pragma unroll
    for (int i = 0; i < 8; ++i) o[i] = f2bf(v[i] * inv);
    const int idx16 = ((ln >> 1) * 16 + (r >> 5)) * 64 + ((ln & 1) << 5) + (r & 31);
    *(int4*)(Apk + idx16 * 8) = *(const int4*)o;
}

// ---- phase 2: per-128-column stripe, fused multi-iteration fixpoint.
// LDS ftB: 16B chunk (g, c) at element (g*NT + c)*8, g = p-granule (p=g*8..+7).
__global__ __launch_bounds__(1024, 4) void ilp_kernel(
        const float* __restrict__ facts,
        const ushort_t* __restrict__ Apk,
        const int* __restrict__ n_iter_p,
        float* __restrict__ out) {
    __shared__ ushort_t ft[64 * NT * 8];   // 131072 B
    __shared__ float wred[2][WAVES][NT];   // 16384 B: per-wave colmax partials, dbuf
    __shared__ float mfin[NT];             // 512 B: final column max for epilogue

    const int tid  = threadIdx.x;
    const int wave = tid >> 6;
    const int lane = tid & 63;
    const int l31  = lane & 31;
    const int half = lane >> 5;
    const int c0   = blockIdx.x * NT;

    int n_iter = *n_iter_p;                // issue scalar load early
    n_iter = n_iter < 0 ? 0 : (n_iter > 8 ? 8 : n_iter);

    // ---- stage: ftB[g][c] = bf16(facts[g*8..+7][c0+c]); linear b128 writes.
    // c = tid&127 spans one wave per 64-col half -> 256B coalesced reads.
    {
        const int c   = tid & 127;
        const int grp = tid >> 7;          // 0..7
        #pragma unroll 2
        for (int s = 0; s < 8; ++s) {
            const int g = grp * 8 + s;
            ushort_t gb[8];
            #pragma unroll
            for (int i = 0; i < 8; ++i)
                gb[i] = f2bf(facts[(g * 8 + i) * CDIM + c0 + c]);
            *(int4*)(&ft[(g * NT + c) * 8]) = *(const int4*)gb;
        }
    }

    // A prologue (kt2=0,1) issued before the barrier: overlaps staging.
    // wave owns rows wave*32 + l31; chunk base = wave*64 + half*32 + l31.
    const ushort_t* abase = Apk + (wave * 64 + half * 32 + l31) * 8;
    bf16x8 aF[2], bR[4];
    aF[0] = *(const bf16x8*)(abase);
    aF[1] = *(const bf16x8*)(abase + 8192);

    __syncthreads();

    // B element base: ((kt2*2 + half)*NT + ct2*32 + l31)*8
    //   = bbase + kt2*2048 + ct2*256
    const int bbase = (half * NT + l31) * 8;
    #pragma unroll
    for (int ct2 = 0; ct2 < 4; ++ct2)
        bR[ct2] = *(const bf16x8*)(&ft[bbase + ct2 * 256]);

    ushort_t ml[4] = {0, 0, 0, 0};         // running colmax, bf16 bits
    float    mf[4] = {0.f, 0.f, 0.f, 0.f}; // running colmax, f32

    #pragma unroll 1
    for (int it = 0; it < n_iter; ++it) {
        f32x16 acc[4];
        #pragma unroll
        for (int ct2 = 0; ct2 < 4; ++ct2)
            #pragma unroll
            for (int e = 0; e < 16; ++e) acc[ct2][e] = 0.f;

        #pragma unroll 2
        for (int kt2 = 0; kt2 < 32; ++kt2) {
            const int cur = kt2 & 1;

            // fold running colmax into this step's B (loaded last step: ready)
            bf16x8 bC[4];
            #pragma unroll
            for (int ct2 = 0; ct2 < 4; ++ct2) bC[ct2] = pkmax8(bR[ct2], ml[ct2]);

            {   // B prefetch k+1 into the same regs (WAR on fold pins order);
                // LDS latency covered by the MFMA round. kt=31 wraps to next iter.
                const int bo = bbase + ((kt2 + 1) & 31) * 2048;
                #pragma unroll
                for (int ct2 = 0; ct2 < 4; ++ct2)
                    bR[ct2] = *(const bf16x8*)(&ft[bo + ct2 * 256]);
            }

            __builtin_amdgcn_s_setprio(1);
            #pragma unroll
            for (int ct2 = 0; ct2 < 4; ++ct2)
                acc[ct2] = __builtin_amdgcn_mfma_f32_32x32x16_bf16(
                    aF[cur], bC[ct2], acc[ct2], 0, 0, 0);
            __builtin_amdgcn_s_setprio(0);

            // A prefetch k+2 into the just-consumed buffer (WAR after MFMA);
            // distance-2 covers L2 latency. Wraps feed next iteration.
            aF[cur] = *(const bf16x8*)(abase + ((kt2 + 2) & 31) * 8192);
        }

        // ---- colmax fold (D: col=lane&31; row identity irrelevant for colmax)
        float mx[4];
        #pragma unroll
        for (int ct2 = 0; ct2 < 4; ++ct2) {
            float m0 = -1e30f;
            #pragma unroll
            for (int e = 0; e < 16; ++e) m0 = fmaxf(m0, acc[ct2][e]);
            m0 = fmaxf(m0, __shfl_xor(m0, 32, 64));
            mx[ct2] = m0;
        }
        const int buf = it & 1;
        if (half == 0) {
            #pragma unroll
            for (int ct2 = 0; ct2 < 4; ++ct2) wred[buf][wave][ct2 * 32 + l31] = mx[ct2];
        }
        __syncthreads();
        #pragma unroll
        for (int ct2 = 0; ct2 < 4; ++ct2) {
            const int c = ct2 * 32 + l31;
            float m = wred[buf][0][c];
            #pragma unroll
            for (int w = 1; w < WAVES; ++w) m = fmaxf(m, wred[buf][w][c]);
            mf[ct2] = fmaxf(mf[ct2], m);    // monotone guard vs bf16 wobble
            ml[ct2] = f2bf(mf[ct2]);
        }
        // no second barrier: wred double-buffered (next write to this buf is
        // beyond the NEXT iteration's barrier, after all reads above).
    }

    // ---- publish final m per column for epilogue layout
    if (wave == 0 && half == 0) {
        #pragma unroll
        for (int ct2 = 0; ct2 < 4; ++ct2) mfin[ct2 * 32 + l31] = mf[ct2];
    }
    __syncthreads();

    // ---- epilogue: out = max(ft, m_final); linear b128 LDS reads, 256B stores
    {
        const int c   = tid & 127;
        const int grp = tid >> 7;
        const float m = mfin[c];
        #pragma unroll 2
        for (int s = 0; s < 8; ++s) {
            const int g = grp * 8 + s;
            ushort_t gb[8];
            *(int4*)gb = *(const int4*)(&ft[(g * NT + c) * 8]);
            #pragma unroll
            for (int i = 0; i < 8; ++i)
                out[(g * 8 + i) * CDIM + c0 + c] = fmaxf(bf2f(gb[i]), m);
        }
    }
}

extern "C" void kernel_launch(void* const* d_in, const int* in_sizes, int n_in,
                              void* d_out, int out_size, void* d_ws, size_t ws_size,
                              hipStream_t stream) {
    const float* facts    = (const float*)d_in[0];       // [512, 65536] fp32
    const float* rw       = (const float*)d_in[1];       // [512, 1, 512] fp32
    const int*   n_iter_p = (const int*)d_in[2];         // scalar 3
    float* out = (float*)d_out;

    ushort_t* Apk = (ushort_t*)d_ws;                     // 512 KB

    softmax_pack<<<PDIM, 64, 0, stream>>>(rw, Apk);
    ilp_kernel<<<CDIM / NT, 1024, 0, stream>>>(facts, Apk, n_iter_p, out);
}

// Round 6
// 309.500 us; speedup vs baseline: 1.0732x; 1.0732x over previous
//
#include <hip/hip_runtime.h>
#include <hip/hip_bf16.h>
#include <cstdint>

// DifferentiableILP on MI355X (gfx950).
// A = softmax(rule_weights[:,0,:]); 3x: facts = max(facts, colmax(A @ facts)).
// Columns independent -> each block owns a 64-col stripe; ft in LDS,
// per-iteration col-max applied to ft via a cheap linear LDS RMW pass.
//
// R8 changes vs R7 (ilp 183us regression; R6 153us baseline, MfmaUtil 28.6%):
//  - Revert to NT=64 / 512-thread / 2-blocks-per-CU (best measured family).
//  - PURE k-loop: the per-k-step pkmax fold (8 VALU + reg copies sitting
//    between B-load and MFMA in every step since R3) is removed. Running
//    col-max is applied to ft ONCE per iteration as a conflict-free LDS RMW
//    (64KB r+w per block ~ 0.6us). k-step = 4 MFMA + 2 ds_read_b128 +
//    2 global_dwordx4 + addressing, nothing on the B->MFMA path.
//  - ft mutates between iterations -> reload B kt0/kt1 after the update
//    barrier (A wrap prefetches remain valid; stale B wraps are dead regs).
//  - stage/epilogue use float2 (2 cols/lane): half the VMEM instructions.
//  - single-buffer wred[8][64] (update barrier orders reuse); no mfin.

typedef __attribute__((ext_vector_type(8))) short bf16x8;   // 8 bf16 = 4 VGPRs
typedef __attribute__((ext_vector_type(8))) unsigned short u16x8;
typedef __attribute__((ext_vector_type(16))) float f32x16;  // 32x32 accumulator
typedef unsigned short ushort_t;
typedef unsigned int uint32;

#define PDIM 512
#define CDIM 65536
#define NT   64      // columns per block
#define WAVES 8

__device__ __forceinline__ ushort_t f2bf(float x) {          // RNE float->bf16
    uint32 u = __float_as_uint(x);
    return (ushort_t)((u + 0x7fffu + ((u >> 16) & 1u)) >> 16);
}
__device__ __forceinline__ float bf2f(uint32 bits) { return __uint_as_float(bits << 16); }

// packed max(v, splat(mu)) in the u16 domain (valid: all values are nonneg bf16)
__device__ __forceinline__ bf16x8 pkmax8(bf16x8 v, ushort_t mu) {
    u16x8 a = __builtin_bit_cast(u16x8, v);
    const u16x8 mb = {mu, mu, mu, mu, mu, mu, mu, mu};
    a = __builtin_elementwise_max(a, mb);
    return __builtin_bit_cast(bf16x8, a);
}

// ---- phase 1: softmax row r, packed fragment-linear for 32x32x16 MFMA.
// chunk idx16 = (kt2*16 + (r>>5))*64 + half*32 + (r&31) holds
// A[r][kt2*16 + half*8 .. +7] as 8 bf16.  (unchanged since R5)
__global__ __launch_bounds__(64) void softmax_pack(const float* __restrict__ rw,
                                                   ushort_t* __restrict__ Apk) {
    const int r  = blockIdx.x;
    const int ln = threadIdx.x;
    const float* row = rw + r * PDIM;
    float4 x0 = *(const float4*)(row + ln * 8);
    float4 x1 = *(const float4*)(row + ln * 8 + 4);
    float v[8] = {x0.x, x0.y, x0.z, x0.w, x1.x, x1.y, x1.z, x1.w};

    float mx = -1e30f;
    #pragma unroll
    for (int i = 0; i < 8; ++i) mx = fmaxf(mx, v[i]);
    #pragma unroll
    for (int d = 1; d < 64; d <<= 1) mx = fmaxf(mx, __shfl_xor(mx, d, 64));
    float s = 0.f;
    #pragma unroll
    for (int i = 0; i < 8; ++i) { v[i] = __expf(v[i] - mx); s += v[i]; }
    #pragma unroll
    for (int d = 1; d < 64; d <<= 1) s += __shfl_xor(s, d, 64);
    const float inv = 1.f / s;

    ushort_t o[8];
    #pragma unroll
    for (int i = 0; i < 8; ++i) o[i] = f2bf(v[i] * inv);
    const int idx16 = ((ln >> 1) * 16 + (r >> 5)) * 64 + ((ln & 1) << 5) + (r & 31);
    *(int4*)(Apk + idx16 * 8) = *(const int4*)o;
}

// ---- phase 2: per-64-column stripe, fused multi-iteration fixpoint.
// LDS ftB: 16B chunk (g, c) at element (g*NT + c)*8, g = p-granule (p=g*8..+7).
__global__ __launch_bounds__(512, 4) void ilp_kernel(
        const float* __restrict__ facts,
        const ushort_t* __restrict__ Apk,
        const int* __restrict__ n_iter_p,
        float* __restrict__ out) {
    __shared__ ushort_t ft[64 * NT * 8];   // 65536 B
    __shared__ float wred[WAVES][NT];      // 2048 B: per-wave colmax partials

    const int tid  = threadIdx.x;
    const int wave = tid >> 6;
    const int lane = tid & 63;
    const int l31  = lane & 31;
    const int half = lane >> 5;
    const int c0   = blockIdx.x * NT;

    int n_iter = *n_iter_p;                // issue scalar load early
    n_iter = n_iter < 0 ? 0 : (n_iter > 8 ? 8 : n_iter);

    wred[wave][lane] = 0.f;                // n_iter==0 safety (512 entries)

    // ---- stage: ftB[g][c] = bf16(facts[g*8..+7][c0+c]); float2 = 2 cols/lane,
    // 512B/wave-instr; LDS writes linear b128 (min 8-accesses/bank pattern).
    {
        const int c2  = (tid & 31) * 2;
        const int grp = tid >> 5;          // 0..15
        #pragma unroll 2
        for (int s = 0; s < 4; ++s) {
            const int g = grp * 4 + s;
            ushort_t ga[8], gb[8];
            #pragma unroll
            for (int i = 0; i < 8; ++i) {
                const float2 v = *(const float2*)(facts + (g * 8 + i) * CDIM + c0 + c2);
                ga[i] = f2bf(v.x);
                gb[i] = f2bf(v.y);
            }
            *(int4*)(&ft[(g * NT + c2) * 8])     = *(const int4*)ga;
            *(int4*)(&ft[(g * NT + c2 + 1) * 8]) = *(const int4*)gb;
        }
    }

    // A prologue (kt2=0,1) issued before the barrier: overlaps staging.
    // row = wave*64 + rt2*32 + l31; element = wave*1024 + rt2*512 + (half*32+l31)*8
    //   + kt2*8192.
    const ushort_t* abase = Apk + wave * 1024 + (half * 32 + l31) * 8;
    bf16x8 aF[2][2], bR[2][2];
    aF[0][0] = *(const bf16x8*)(abase);
    aF[0][1] = *(const bf16x8*)(abase + 512);
    aF[1][0] = *(const bf16x8*)(abase + 8192);
    aF[1][1] = *(const bf16x8*)(abase + 8192 + 512);

    __syncthreads();

    // B element base: ((kt2*2+half)*NT + ct2*32 + l31)*8 = bbase + kt2*1024 + ct2*256
    const int bbase = (half * NT + l31) * 8;
    bR[0][0] = *(const bf16x8*)(&ft[bbase]);
    bR[0][1] = *(const bf16x8*)(&ft[bbase + 256]);
    bR[1][0] = *(const bf16x8*)(&ft[bbase + 1024]);
    bR[1][1] = *(const bf16x8*)(&ft[bbase + 1024 + 256]);

    #pragma unroll 1
    for (int it = 0; it < n_iter; ++it) {
        f32x16 acc[2][2];
        #pragma unroll
        for (int rt2 = 0; rt2 < 2; ++rt2)
            #pragma unroll
            for (int ct2 = 0; ct2 < 2; ++ct2)
                #pragma unroll
                for (int e = 0; e < 16; ++e) acc[rt2][ct2][e] = 0.f;

        // ---- PURE k-loop: nothing between fragments and MFMA.
        #pragma unroll 2
        for (int kt2 = 0; kt2 < 32; ++kt2) {
            const int cur = kt2 & 1;

            __builtin_amdgcn_s_setprio(1);
            acc[0][0] = __builtin_amdgcn_mfma_f32_32x32x16_bf16(
                aF[cur][0], bR[cur][0], acc[0][0], 0, 0, 0);
            acc[1][0] = __builtin_amdgcn_mfma_f32_32x32x16_bf16(
                aF[cur][1], bR[cur][0], acc[1][0], 0, 0, 0);
            acc[0][1] = __builtin_amdgcn_mfma_f32_32x32x16_bf16(
                aF[cur][0], bR[cur][1], acc[0][1], 0, 0, 0);
            acc[1][1] = __builtin_amdgcn_mfma_f32_32x32x16_bf16(
                aF[cur][1], bR[cur][1], acc[1][1], 0, 0, 0);
            __builtin_amdgcn_s_setprio(0);

            // distance-2 prefetch into just-consumed buffers (WAR-pinned after
            // the MFMA cluster). At 4 waves/SIMD a wave's MFMA round ~512cy:
            // covers L2 (~300cy) and LDS (~120cy) easily. Wraps at kt=30/31
            // feed next iteration (A valid; B stale -> reloaded post-update).
            const int ktp = (kt2 + 2) & 31;
            const ushort_t* ap = abase + ktp * 8192;
            aF[cur][0] = *(const bf16x8*)(ap);
            aF[cur][1] = *(const bf16x8*)(ap + 512);
            const int bo = bbase + ktp * 1024;
            bR[cur][0] = *(const bf16x8*)(&ft[bo]);
            bR[cur][1] = *(const bf16x8*)(&ft[bo + 256]);
        }

        // ---- colmax fold (D: col=lane&31; row identity irrelevant for colmax)
        #pragma unroll
        for (int ct2 = 0; ct2 < 2; ++ct2) {
            float m0 = -1e30f;
            #pragma unroll
            for (int rt2 = 0; rt2 < 2; ++rt2)
                #pragma unroll
                for (int e = 0; e < 16; ++e) m0 = fmaxf(m0, acc[rt2][ct2][e]);
            m0 = fmaxf(m0, __shfl_xor(m0, 32, 64));
            if (half == 0) wred[wave][ct2 * 32 + l31] = m0;
        }
        __syncthreads();

        if (it < n_iter - 1) {
            // ---- update pass: ft[*][c] = max(ft[*][c], m(c)); one thread per
            // (wave-g-group, column): linear b128 RMW, conflict-free.
            const int c = tid & 63;
            float m = wred[0][c];
            #pragma unroll
            for (int w = 1; w < WAVES; ++w) m = fmaxf(m, wred[w][c]);
            const ushort_t mu = f2bf(m);
            #pragma unroll
            for (int s = 0; s < 8; ++s) {
                const int idx = ((wave * 8 + s) * NT + c) * 8;
                bf16x8 v = *(const bf16x8*)(&ft[idx]);
                *(bf16x8*)(&ft[idx]) = pkmax8(v, mu);
            }
            __syncthreads();
            // reload B kt0/kt1 (post-update ft); A wraps already valid.
            bR[0][0] = *(const bf16x8*)(&ft[bbase]);
            bR[0][1] = *(const bf16x8*)(&ft[bbase + 256]);
            bR[1][0] = *(const bf16x8*)(&ft[bbase + 1024]);
            bR[1][1] = *(const bf16x8*)(&ft[bbase + 1024 + 256]);
        }
    }

    // ---- epilogue: out = max(ft, m_final); m recomputed from wred (already
    // barriered by the last fold). float2 stores, 2 cols/lane.
    {
        const int c2  = (tid & 31) * 2;
        const int grp = tid >> 5;
        float m0 = wred[0][c2], m1 = wred[0][c2 + 1];
        #pragma unroll
        for (int w = 1; w < WAVES; ++w) {
            m0 = fmaxf(m0, wred[w][c2]);
            m1 = fmaxf(m1, wred[w][c2 + 1]);
        }
        #pragma unroll 2
        for (int s = 0; s < 4; ++s) {
            const int g = grp * 4 + s;
            ushort_t ga[8], gb[8];
            *(int4*)ga = *(const int4*)(&ft[(g * NT + c2) * 8]);
            *(int4*)gb = *(const int4*)(&ft[(g * NT + c2 + 1) * 8]);
            #pragma unroll
            for (int i = 0; i < 8; ++i) {
                float2 v;
                v.x = fmaxf(bf2f(ga[i]), m0);
                v.y = fmaxf(bf2f(gb[i]), m1);
                *(float2*)(out + (g * 8 + i) * CDIM + c0 + c2) = v;
            }
        }
    }
}

extern "C" void kernel_launch(void* const* d_in, const int* in_sizes, int n_in,
                              void* d_out, int out_size, void* d_ws, size_t ws_size,
                              hipStream_t stream) {
    const float* facts    = (const float*)d_in[0];       // [512, 65536] fp32
    const float* rw       = (const float*)d_in[1];       // [512, 1, 512] fp32
    const int*   n_iter_p = (const int*)d_in[2];         // scalar 3
    float* out = (float*)d_out;

    ushort_t* Apk = (ushort_t*)d_ws;                     // 512 KB

    softmax_pack<<<PDIM, 64, 0, stream>>>(rw, Apk);
    ilp_kernel<<<CDIM / NT, 512, 0, stream>>>(facts, Apk, n_iter_p, out);
}

// Round 7
// 308.174 us; speedup vs baseline: 1.0778x; 1.0043x over previous
//
#include <hip/hip_runtime.h>
#include <hip/hip_bf16.h>
#include <cstdint>

// DifferentiableILP on MI355X (gfx950).
// A = softmax(rule_weights[:,0,:]); 3x: facts = max(facts, colmax(A @ facts)).
// Columns independent -> each block owns a column stripe; ft in LDS,
// per-iteration col-max applied to ft via a linear LDS RMW pass.
//
// R9 changes vs R8 (ilp 160us, MfmaUtil 27%, conflicts 7.6M):
//  - Feed analysis: MFMA-busy is 43-44us (the floor) in EVERY config R2-R8;
//    duration is set by the GEMM's two feeds:
//      A-from-L2: 1KB/ct2 per MFMA. NT=64 (ct2=2) demands 39 TB/s = 112% of
//        the L2 ceiling -> all NT=64 configs flat at ~150-160us.
//      B-from-LDS: 1KB/rt2 per MFMA. R7 (rt2=1) demanded 128 B/cy/CU = 150%
//        of measured LDS throughput -> R7's regression (my L2 test was
//        confounded by this, not by 1 block/CU alone).
//    Unique feasible point under acc<=128 AGPR: rt2=2 x ct2=4 -> NT=128,
//    8 waves x 64 rows, 512 thr, 1 block/CU, 2 waves/SIMD.
//    A-demand -> 19.7 TB/s (57% L2); LDS -> 64 B/cy/CU (75% measured).
//  - Stage/epilogue back to 1 col/lane (256B contiguous both sides) -- R8's
//    float2 variant was the 7.6M-conflict source (32B-strided b128).
//  - Pure k-loop + per-iteration update pass retained from R8.

typedef __attribute__((ext_vector_type(8))) short bf16x8;   // 8 bf16 = 4 VGPRs
typedef __attribute__((ext_vector_type(8))) unsigned short u16x8;
typedef __attribute__((ext_vector_type(16))) float f32x16;  // 32x32 accumulator
typedef unsigned short ushort_t;
typedef unsigned int uint32;

#define PDIM 512
#define CDIM 65536
#define NT   128     // columns per block
#define WAVES 8

__device__ __forceinline__ ushort_t f2bf(float x) {          // RNE float->bf16
    uint32 u = __float_as_uint(x);
    return (ushort_t)((u + 0x7fffu + ((u >> 16) & 1u)) >> 16);
}
__device__ __forceinline__ float bf2f(uint32 bits) { return __uint_as_float(bits << 16); }

// packed max(v, splat(mu)) in the u16 domain (valid: all values are nonneg bf16)
__device__ __forceinline__ bf16x8 pkmax8(bf16x8 v, ushort_t mu) {
    u16x8 a = __builtin_bit_cast(u16x8, v);
    const u16x8 mb = {mu, mu, mu, mu, mu, mu, mu, mu};
    a = __builtin_elementwise_max(a, mb);
    return __builtin_bit_cast(bf16x8, a);
}

// ---- phase 1: softmax row r, packed fragment-linear for 32x32x16 MFMA.
// chunk idx16 = kt2*1024 + (r>>5)*64 + (ln&1)*32 + (r&31) holds
// A[r][kt2*16 + (ln&1)*8 .. +7] as 8 bf16.  (unchanged since R5)
__global__ __launch_bounds__(64) void softmax_pack(const float* __restrict__ rw,
                                                   ushort_t* __restrict__ Apk) {
    const int r  = blockIdx.x;
    const int ln = threadIdx.x;
    const float* row = rw + r * PDIM;
    float4 x0 = *(const float4*)(row + ln * 8);
    float4 x1 = *(const float4*)(row + ln * 8 + 4);
    float v[8] = {x0.x, x0.y, x0.z, x0.w, x1.x, x1.y, x1.z, x1.w};

    float mx = -1e30f;
    #pragma unroll
    for (int i = 0; i < 8; ++i) mx = fmaxf(mx, v[i]);
    #pragma unroll
    for (int d = 1; d < 64; d <<= 1) mx = fmaxf(mx, __shfl_xor(mx, d, 64));
    float s = 0.f;
    #pragma unroll
    for (int i = 0; i < 8; ++i) { v[i] = __expf(v[i] - mx); s += v[i]; }
    #pragma unroll
    for (int d = 1; d < 64; d <<= 1) s += __shfl_xor(s, d, 64);
    const float inv = 1.f / s;

    ushort_t o[8];
    #pragma unroll
    for (int i = 0; i < 8; ++i) o[i] = f2bf(v[i] * inv);
    const int idx16 = ((ln >> 1) * 16 + (r >> 5)) * 64 + ((ln & 1) << 5) + (r & 31);
    *(int4*)(Apk + idx16 * 8) = *(const int4*)o;
}

// ---- phase 2: per-128-column stripe, fused multi-iteration fixpoint.
// LDS ftB: 16B chunk (g, c) at element (g*NT + c)*8, g = p-granule (p=g*8..+7).
__global__ __launch_bounds__(512, 2) void ilp_kernel(
        const float* __restrict__ facts,
        const ushort_t* __restrict__ Apk,
        const int* __restrict__ n_iter_p,
        float* __restrict__ out) {
    __shared__ ushort_t ft[64 * NT * 8];   // 131072 B
    __shared__ float wred[WAVES][NT];      // 4096 B: per-wave colmax partials

    const int tid  = threadIdx.x;
    const int wave = tid >> 6;
    const int lane = tid & 63;
    const int l31  = lane & 31;
    const int half = lane >> 5;
    const int c0   = blockIdx.x * NT;

    int n_iter = *n_iter_p;                // issue scalar load early
    n_iter = n_iter < 0 ? 0 : (n_iter > 8 ? 8 : n_iter);

    wred[wave][lane]      = 0.f;           // n_iter==0 safety (8x128 entries)
    wred[wave][lane + 64] = 0.f;

    // ---- stage: ftB[g][c] = bf16(facts[g*8..+7][c0+c]); 1 col/lane.
    // Global: 256B/wave-instr coalesced. LDS: 16 consecutive lanes span 256B
    // contiguous -> conflict-free b128 writes.
    {
        const int c   = tid & 127;
        const int grp = tid >> 7;          // 0..3
        #pragma unroll 4
        for (int s = 0; s < 16; ++s) {
            const int g = grp * 16 + s;
            ushort_t gb[8];
            #pragma unroll
            for (int i = 0; i < 8; ++i)
                gb[i] = f2bf(facts[(g * 8 + i) * CDIM + c0 + c]);
            *(int4*)(&ft[(g * NT + c) * 8]) = *(const int4*)gb;
        }
    }

    // A prologue (kt2=0,1) issued before the barrier: overlaps staging.
    // wave owns rows wave*64 + rt2*32 + l31;
    // element = wave*1024 + rt2*512 + (half*32+l31)*8 + kt2*8192.
    const ushort_t* abase = Apk + wave * 1024 + (half * 32 + l31) * 8;
    bf16x8 aF[2][2], bR[2][4];
    aF[0][0] = *(const bf16x8*)(abase);
    aF[0][1] = *(const bf16x8*)(abase + 512);
    aF[1][0] = *(const bf16x8*)(abase + 8192);
    aF[1][1] = *(const bf16x8*)(abase + 8192 + 512);

    __syncthreads();

    // B element base: ((kt2*2+half)*NT + ct2*32 + l31)*8 = bbase + kt2*2048 + ct2*256
    const int bbase = (half * NT + l31) * 8;
    #pragma unroll
    for (int ct2 = 0; ct2 < 4; ++ct2) {
        bR[0][ct2] = *(const bf16x8*)(&ft[bbase + ct2 * 256]);
        bR[1][ct2] = *(const bf16x8*)(&ft[bbase + 2048 + ct2 * 256]);
    }

    #pragma unroll 1
    for (int it = 0; it < n_iter; ++it) {
        f32x16 acc[2][4];
        #pragma unroll
        for (int rt2 = 0; rt2 < 2; ++rt2)
            #pragma unroll
            for (int ct2 = 0; ct2 < 4; ++ct2)
                #pragma unroll
                for (int e = 0; e < 16; ++e) acc[rt2][ct2][e] = 0.f;

        // ---- PURE k-loop: 8 MFMA + 2 global b128 (A) + 4 LDS b128 (B) per step.
        #pragma unroll 2
        for (int kt2 = 0; kt2 < 32; ++kt2) {
            const int cur = kt2 & 1;

            __builtin_amdgcn_s_setprio(1);
            #pragma unroll
            for (int ct2 = 0; ct2 < 4; ++ct2) {
                acc[0][ct2] = __builtin_amdgcn_mfma_f32_32x32x16_bf16(
                    aF[cur][0], bR[cur][ct2], acc[0][ct2], 0, 0, 0);
                acc[1][ct2] = __builtin_amdgcn_mfma_f32_32x32x16_bf16(
                    aF[cur][1], bR[cur][ct2], acc[1][ct2], 0, 0, 0);
            }
            __builtin_amdgcn_s_setprio(0);

            // distance-2 prefetch into just-consumed buffers (WAR-pinned after
            // the MFMA cluster). Wave cadence ~512cy at 2 waves/SIMD -> 1024cy
            // in-flight covers L2 (~300cy) and LDS (~120cy). Wraps at kt=30/31
            // feed next iteration (A valid; B stale -> reloaded post-update).
            const int ktp = (kt2 + 2) & 31;
            const ushort_t* ap = abase + ktp * 8192;
            aF[cur][0] = *(const bf16x8*)(ap);
            aF[cur][1] = *(const bf16x8*)(ap + 512);
            const int bo = bbase + ktp * 2048;
            #pragma unroll
            for (int ct2 = 0; ct2 < 4; ++ct2)
                bR[cur][ct2] = *(const bf16x8*)(&ft[bo + ct2 * 256]);
        }

        // ---- colmax fold (D: col=lane&31; row identity irrelevant for colmax)
        #pragma unroll
        for (int ct2 = 0; ct2 < 4; ++ct2) {
            float m0 = -1e30f;
            #pragma unroll
            for (int rt2 = 0; rt2 < 2; ++rt2)
                #pragma unroll
                for (int e = 0; e < 16; ++e) m0 = fmaxf(m0, acc[rt2][ct2][e]);
            m0 = fmaxf(m0, __shfl_xor(m0, 32, 64));
            if (half == 0) wred[wave][ct2 * 32 + l31] = m0;
        }
        __syncthreads();

        if (it < n_iter - 1) {
            // ---- update pass: ft[*][c] = max(ft[*][c], m(c)); linear b128 RMW,
            // 16 consecutive lanes span 256B -> conflict-free.
            const int c   = tid & 127;
            const int grp = tid >> 7;
            float m = wred[0][c];
            #pragma unroll
            for (int w = 1; w < WAVES; ++w) m = fmaxf(m, wred[w][c]);
            const ushort_t mu = f2bf(m);
            #pragma unroll
            for (int s = 0; s < 16; ++s) {
                const int idx = ((grp * 16 + s) * NT + c) * 8;
                bf16x8 v = *(const bf16x8*)(&ft[idx]);
                *(bf16x8*)(&ft[idx]) = pkmax8(v, mu);
            }
            __syncthreads();
            // reload B kt0/kt1 (post-update ft); A wraps already valid.
            #pragma unroll
            for (int ct2 = 0; ct2 < 4; ++ct2) {
                bR[0][ct2] = *(const bf16x8*)(&ft[bbase + ct2 * 256]);
                bR[1][ct2] = *(const bf16x8*)(&ft[bbase + 2048 + ct2 * 256]);
            }
        }
    }

    // ---- epilogue: out = max(ft, m_final); m from wred (barriered by the
    // last fold). 1 col/lane, 256B coalesced stores, conflict-free LDS reads.
    {
        const int c   = tid & 127;
        const int grp = tid >> 7;
        float m = wred[0][c];
        #pragma unroll
        for (int w = 1; w < WAVES; ++w) m = fmaxf(m, wred[w][c]);
        #pragma unroll 4
        for (int s = 0; s < 16; ++s) {
            const int g = grp * 16 + s;
            ushort_t gb[8];
            *(int4*)gb = *(const int4*)(&ft[(g * NT + c) * 8]);
            #pragma unroll
            for (int i = 0; i < 8; ++i)
                out[(g * 8 + i) * CDIM + c0 + c] = fmaxf(bf2f(gb[i]), m);
        }
    }
}

extern "C" void kernel_launch(void* const* d_in, const int* in_sizes, int n_in,
                              void* d_out, int out_size, void* d_ws, size_t ws_size,
                              hipStream_t stream) {
    const float* facts    = (const float*)d_in[0];       // [512, 65536] fp32
    const float* rw       = (const float*)d_in[1];       // [512, 1, 512] fp32
    const int*   n_iter_p = (const int*)d_in[2];         // scalar 3
    float* out = (float*)d_out;

    ushort_t* Apk = (ushort_t*)d_ws;                     // 512 KB

    softmax_pack<<<PDIM, 64, 0, stream>>>(rw, Apk);
    ilp_kernel<<<CDIM / NT, 512, 0, stream>>>(facts, Apk, n_iter_p, out);
}